// Round 8
// baseline (291.547 us; speedup 1.0000x reference)
//
#include <hip/hip_runtime.h>
#include <math.h>

// Problem constants (static per reference)
#define B_    256
#define N_    400
#define D_    256
#define EPG_  12800          // N*DEG edges per graph (block-diagonal, contiguous)
#define E_    3276800        // B*EPG
#define NT_   102400         // B*N
#define K_    200            // ceil(0.5*N)
#define NKC_  200            // N-K
#define NSLAB_ 2048          // edge slabs (8 per graph)
#define I4PS_  400           // int4s per slab (1600 edges)

// Output flat offsets (float32 elements, in return order).
#define O_FDIS 0
#define O_FCOM 13107200      // + B*K*D
#define O_PERM 26214400      // + B*NKC*D
#define O_PCOM 26265600      // + B*K
#define O_SOFT 26316800      // + B*NKC
#define O_EDIS 26419200      // + NT
#define O_ECOM 29696000      // + E

#define NEG_INF (-3.402823466e38f)

// Native clang vector for __builtin_nontemporal_store (rejects HIP float4).
typedef float nfv4 __attribute__((ext_vector_type(4)));
static __device__ __forceinline__ void nt_store4(float4* p, float4 v) {
    nfv4 x; x.x = v.x; x.y = v.y; x.z = v.z; x.w = v.w;
    __builtin_nontemporal_store(x, (nfv4*)p);
}

// ---------------------------------------------------------------------------
// A: two populations, hist FIRST so its latency hides under the feat stream.
//   blocks [0,512):      degree histograms, WAVE-PRIVATE end-to-end:
//                        each wave owns one 1600-edge slab + its own LDS
//                        count pair; zero -> count -> write partial with NO
//                        barriers. 8 partials per graph per table.
//   blocks [512,6912):   hraw[n] = dot(feat[n],W)  (105 MB stream, ~6.2TB/s)
// ---------------------------------------------------------------------------
__global__ __launch_bounds__(256) void k_A(const float* __restrict__ feat,
                                           const float* __restrict__ W,
                                           const int* __restrict__ src,
                                           const int* __restrict__ dst,
                                           float* __restrict__ hraw,
                                           int* __restrict__ degp_o,
                                           int* __restrict__ degp_i) {
    const int bid = blockIdx.x, tid = threadIdx.x;
    if (bid < NSLAB_ / 4) {
        // --- histogram population (4 waves/block, each fully independent)
        __shared__ int hp[4][2][N_];           // 12.8 KB, [wave][o|i][node]
        const int wave = tid >> 6, lane = tid & 63;
        const int slab = bid * 4 + wave;       // [0, 2048); 8 slabs/graph
        const int nbase = (slab >> 3) * N_;
        int* mo = hp[wave][0];
        int* mi = hp[wave][1];
        for (int t = lane; t < N_; t += 64) { mo[t] = 0; mi[t] = 0; }
        const int4* s4 = (const int4*)src + slab * I4PS_;
        const int4* d4 = (const int4*)dst + slab * I4PS_;
        for (int i = lane; i < I4PS_; i += 64) {
            int4 s = s4[i]; int4 d = d4[i];
            atomicAdd(&mo[s.x - nbase], 1);
            atomicAdd(&mo[s.y - nbase], 1);
            atomicAdd(&mo[s.z - nbase], 1);
            atomicAdd(&mo[s.w - nbase], 1);
            atomicAdd(&mi[d.x - nbase], 1);
            atomicAdd(&mi[d.y - nbase], 1);
            atomicAdd(&mi[d.z - nbase], 1);
            atomicAdd(&mi[d.w - nbase], 1);
        }
        for (int t = lane; t < N_; t += 64) {
            degp_o[slab * N_ + t] = mo[t];
            degp_i[slab * N_ + t] = mi[t];
        }
    } else {
        // --- dot population
        const int rb = bid - NSLAB_ / 4;       // [0, 6400)
        const int gw   = (rb * 256 + tid) >> 6;
        const int lane = tid & 63;
        const float4 w4 = ((const float4*)W)[lane];
        const int r0 = gw * 4;
        const float4* fb = (const float4*)feat;
        float4 a0 = fb[(size_t)(r0    ) * 64 + lane];
        float4 a1 = fb[(size_t)(r0 + 1) * 64 + lane];
        float4 a2 = fb[(size_t)(r0 + 2) * 64 + lane];
        float4 a3 = fb[(size_t)(r0 + 3) * 64 + lane];
        float d0 = a0.x*w4.x + a0.y*w4.y + a0.z*w4.z + a0.w*w4.w;
        float d1 = a1.x*w4.x + a1.y*w4.y + a1.z*w4.z + a1.w*w4.w;
        float d2 = a2.x*w4.x + a2.y*w4.y + a2.z*w4.z + a2.w*w4.w;
        float d3 = a3.x*w4.x + a3.y*w4.y + a3.z*w4.z + a3.w*w4.w;
        #pragma unroll
        for (int off = 32; off > 0; off >>= 1) {
            d0 += __shfl_down(d0, off, 64);
            d1 += __shfl_down(d1, off, 64);
            d2 += __shfl_down(d2, off, 64);
            d3 += __shfl_down(d3, off, 64);
        }
        if (lane == 0) {
            hraw[r0    ] = d0;
            hraw[r0 + 1] = d1;
            hraw[r0 + 2] = d2;
            hraw[r0 + 3] = d3;
        }
    }
}

// ---------------------------------------------------------------------------
// B: scatter partials, wave-private slabs. 512 blocks x 256 thr; block bid
// handles slabs [bid*4, bid*4+4) — all in graph bid>>1. One shared hl table
// (built from hraw + 8 degp_o partials), ONE barrier, then each wave
// scatters its slab into its private float array and writes its partial.
// ---------------------------------------------------------------------------
__global__ __launch_bounds__(256) void k_B(const int* __restrict__ src,
                                           const int* __restrict__ dst,
                                           const float* __restrict__ hraw,
                                           const int* __restrict__ degp_o,
                                           float* __restrict__ aggp) {
    __shared__ float hl[N_];
    __shared__ float sp[4][N_];                // 6.4 KB wave-private partials
    const int bid = blockIdx.x, tid = threadIdx.x;
    const int wave = tid >> 6, lane = tid & 63;
    const int g = bid >> 1, nbase = g * N_, g8 = g * 8;

    for (int t = tid; t < N_; t += 256) {
        int dsum = 0;
        #pragma unroll
        for (int q = 0; q < 8; ++q) dsum += degp_o[(g8 + q) * N_ + t];
        hl[t] = hraw[nbase + t] * (1.0f / sqrtf(fmaxf((float)dsum, 1.0f)));
    }
    for (int t = lane; t < N_; t += 64) sp[wave][t] = 0.0f;
    __syncthreads();                           // hl complete; own sp zeroed

    const int slab = bid * 4 + wave;
    float* spw = sp[wave];
    const int4* s4 = (const int4*)src + slab * I4PS_;
    const int4* d4 = (const int4*)dst + slab * I4PS_;
    for (int i = lane; i < I4PS_; i += 64) {
        int4 s = s4[i]; int4 d = d4[i];
        atomicAdd(&spw[d.x - nbase], hl[s.x - nbase]);
        atomicAdd(&spw[d.y - nbase], hl[s.y - nbase]);
        atomicAdd(&spw[d.z - nbase], hl[s.z - nbase]);
        atomicAdd(&spw[d.w - nbase], hl[s.w - nbase]);
    }
    // wave-private: no second barrier needed
    for (int t = lane; t < N_; t += 64)
        aggp[slab * N_ + t] = spw[t];
}

// ---------------------------------------------------------------------------
// C: per-graph score + top-k. 256 blocks x 512 thr. score = (Σ8 aggp) *
// rsqrt(max(Σ8 degp_i,1)) + b. Rank-select via readlane (pure VALU);
// rank == lax.top_k stable-descending position. Complement via ballots.
// Wave 7 does the softmax partial.
// ---------------------------------------------------------------------------
__global__ __launch_bounds__(512) void k_C(const float* __restrict__ aggp,
                                           const int* __restrict__ degp_i,
                                           const float* __restrict__ bp,
                                           float* __restrict__ score,
                                           float* __restrict__ pm,
                                           float* __restrict__ ps,
                                           int* __restrict__ sel,
                                           int* __restrict__ orow,
                                           float* __restrict__ out) {
    __shared__ float scl[N_];
    __shared__ unsigned long long bmask[7];
    const int g = blockIdx.x, tid = threadIdx.x;
    const int wave = tid >> 6, lane = tid & 63;
    const int nbase = g * N_, g8 = g * 8;

    const float bb = bp[0];
    if (tid < N_) {
        float a = 0.0f; int dsum = 0;
        #pragma unroll
        for (int q = 0; q < 8; ++q) {
            a    += aggp  [(g8 + q) * N_ + tid];
            dsum += degp_i[(g8 + q) * N_ + tid];
        }
        const float v = a * (1.0f / sqrtf(fmaxf((float)dsum, 1.0f))) + bb;
        score[nbase + tid] = v;
        scl[tid] = v;
    }
    __syncthreads();

    bool selb = false;
    if (tid < 448) {             // waves 0-6
        float sreg[7];
        #pragma unroll
        for (int t = 0; t < 7; ++t) {
            const int j = t * 64 + lane;
            sreg[t] = (j < N_) ? scl[j] : NEG_INF;
        }
        const float v = (tid < N_) ? scl[tid] : NEG_INF;
        int rnk = 0;
        #pragma unroll
        for (int t = 0; t < 7; ++t) {
            #pragma unroll
            for (int l2 = 0; l2 < 64; ++l2) {
                const int j = t * 64 + l2;
                if (j < N_) {    // compile-time prune (t=6, l2>=16)
                    const float u = __uint_as_float(
                        __builtin_amdgcn_readlane(__float_as_uint(sreg[t]), l2));
                    rnk += ((u > v) || (u == v && j < tid)) ? 1 : 0;
                }
            }
        }
        selb = (tid < N_) && (rnk < K_);
        if (tid < N_) sel[nbase + tid] = selb ? 1 : 0;
        if (selb) {
            orow[nbase + tid] = g * K_ + rnk;               // dis rows [0,B*K)
            out[O_PERM + g * K_ + rnk] = (float)(nbase + tid);
        }
        unsigned long long bal = __ballot(selb);
        if (lane == 0) bmask[wave] = bal;
    }
    // Wave 7: per-graph softmax partial (reads scl only).
    if (wave == 7) {
        float m = NEG_INF;
        for (int i = lane; i < N_; i += 64) m = fmaxf(m, scl[i]);
        #pragma unroll
        for (int o = 32; o > 0; o >>= 1) m = fmaxf(m, __shfl_xor(m, o, 64));
        float s = 0.0f;
        for (int i = lane; i < N_; i += 64) s += expf(scl[i] - m);
        #pragma unroll
        for (int o = 32; o > 0; o >>= 1) s += __shfl_xor(s, o, 64);
        if (lane == 0) { pm[g] = m; ps[g] = s; }
    }
    __syncthreads();

    // Complement positions from ballots: pos = tid - #selected_below
    if (tid < N_ && !selb) {
        int nsel = 0;
        #pragma unroll
        for (int w = 0; w < 7; ++w)
            if (w < wave) nsel += (int)__popcll(bmask[w]);
        nsel += (int)__popcll(bmask[wave] & ((1ull << lane) - 1ull));
        const int pos = tid - nsel;
        orow[nbase + tid] = B_ * K_ + g * NKC_ + pos;       // com rows
        out[O_PCOM + g * NKC_ + pos] = (float)(nbase + tid);
    }
}

// ---------------------------------------------------------------------------
// D: two populations:
//   blocks [0,6400):    gated gather (feat L3-hot, nt row stores) with
//                       per-block softmax combine from pm/ps (2 KB, L2-hot)
//   blocks [6400,9600): edge masks (edges L3-hot, sel L2-hot, nt stores)
// ---------------------------------------------------------------------------
__global__ __launch_bounds__(256) void k_D(const float* __restrict__ feat,
                                           const float* __restrict__ score,
                                           const int* __restrict__ orow,
                                           const float* __restrict__ pm,
                                           const float* __restrict__ ps,
                                           const int* __restrict__ src,
                                           const int* __restrict__ dst,
                                           const int* __restrict__ sel,
                                           float* __restrict__ out) {
    const int bid = blockIdx.x, tid = threadIdx.x;
    if (bid < NT_ / 16) {
        __shared__ float sm[4], ss[4];
        const int lane = tid & 63, wv = tid >> 6;
        float m = pm[tid], s = ps[tid];
        #pragma unroll
        for (int o = 32; o > 0; o >>= 1) {
            float mo = __shfl_xor(m, o, 64);
            float so = __shfl_xor(s, o, 64);
            float M2 = fmaxf(m, mo);
            s = s * expf(m - M2) + so * expf(mo - M2);
            m = M2;
        }
        if (lane == 0) { sm[wv] = m; ss[wv] = s; }
        __syncthreads();
        const float M = fmaxf(fmaxf(sm[0], sm[1]), fmaxf(sm[2], sm[3]));
        const float S = ss[0] * expf(sm[0] - M) + ss[1] * expf(sm[1] - M)
                      + ss[2] * expf(sm[2] - M) + ss[3] * expf(sm[3] - M);

        const int gw = (bid * 256 + tid) >> 6;
        const int n0 = gw * 4;
        const float4* fb = (const float4*)feat;
        float4 v0 = fb[(size_t)(n0    ) * 64 + lane];
        float4 v1 = fb[(size_t)(n0 + 1) * 64 + lane];
        float4 v2 = fb[(size_t)(n0 + 2) * 64 + lane];
        float4 v3 = fb[(size_t)(n0 + 3) * 64 + lane];
        float s0 = score[n0], s1 = score[n0 + 1], s2 = score[n0 + 2], s3 = score[n0 + 3];
        int   r0 = orow[n0],  r1 = orow[n0 + 1],  r2 = orow[n0 + 2],  r3 = orow[n0 + 3];
        float t0 = tanhf(s0), t1 = tanhf(s1), t2 = tanhf(s2), t3 = tanhf(s3);
        v0.x *= t0; v0.y *= t0; v0.z *= t0; v0.w *= t0;
        v1.x *= t1; v1.y *= t1; v1.z *= t1; v1.w *= t1;
        v2.x *= t2; v2.y *= t2; v2.z *= t2; v2.w *= t2;
        v3.x *= t3; v3.y *= t3; v3.z *= t3; v3.w *= t3;
        nt_store4(((float4*)(out + (size_t)r0 * D_)) + lane, v0);
        nt_store4(((float4*)(out + (size_t)r1 * D_)) + lane, v1);
        nt_store4(((float4*)(out + (size_t)r2 * D_)) + lane, v2);
        nt_store4(((float4*)(out + (size_t)r3 * D_)) + lane, v3);
        if (lane == 0) {
            out[O_SOFT + n0    ] = expf(s0 - M) / S;
            out[O_SOFT + n0 + 1] = expf(s1 - M) / S;
            out[O_SOFT + n0 + 2] = expf(s2 - M) / S;
            out[O_SOFT + n0 + 3] = expf(s3 - M) / S;
        }
    } else {
        const int i = (bid - NT_ / 16) * 256 + tid;   // 0 .. E/4-1
        int4 s = ((const int4*)src)[i];
        int4 d = ((const int4*)dst)[i];
        int a0 = sel[s.x], a1 = sel[s.y], a2 = sel[s.z], a3 = sel[s.w];
        int b0 = sel[d.x], b1 = sel[d.y], b2 = sel[d.z], b3 = sel[d.w];
        float4 mdis, mcom;
        mdis.x = (a0 & b0) ? 1.0f : 0.0f;  mcom.x = (a0 | b0) ? 0.0f : 1.0f;
        mdis.y = (a1 & b1) ? 1.0f : 0.0f;  mcom.y = (a1 | b1) ? 0.0f : 1.0f;
        mdis.z = (a2 & b2) ? 1.0f : 0.0f;  mcom.z = (a2 | b2) ? 0.0f : 1.0f;
        mdis.w = (a3 & b3) ? 1.0f : 0.0f;  mcom.w = (a3 | b3) ? 0.0f : 1.0f;
        nt_store4(((float4*)(out + O_EDIS)) + i, mdis);
        nt_store4(((float4*)(out + O_ECOM)) + i, mcom);
    }
}

extern "C" void kernel_launch(void* const* d_in, const int* in_sizes, int n_in,
                              void* d_out, int out_size, void* d_ws, size_t ws_size,
                              hipStream_t stream) {
    const float* feat = (const float*)d_in[0];
    const float* W    = (const float*)d_in[1];
    const float* bp   = (const float*)d_in[2];
    const int*   src  = (const int*)d_in[3];
    const int*   dst  = (const int*)d_in[4];
    float* out = (float*)d_out;

    // Workspace (no aliasing, no zero-init anywhere):
    char* ws = (char*)d_ws;
    float* hraw   = (float*)(ws + 0);          // NT floats         (400 KB)
    int*   degp_o = (int*)  (ws + 409600);     // NSLAB*N ints      (3.28 MB)
    int*   degp_i = (int*)  (ws + 3686400);    // NSLAB*N ints      (3.28 MB)
    float* aggp   = (float*)(ws + 6963200);    // NSLAB*N floats    (3.28 MB)
    float* score  = (float*)(ws + 10240000);   // NT floats
    int*   sel    = (int*)  (ws + 10649600);   // NT ints
    int*   orow   = (int*)  (ws + 11059200);   // NT ints
    float* pm     = (float*)(ws + 11468800);   // B floats
    float* ps     = (float*)(ws + 11469824);   // B floats

    k_A<<<NSLAB_ / 4 + NT_ / 16,   256, 0, stream>>>(feat, W, src, dst,
                                                     hraw, degp_o, degp_i);
    k_B<<<NSLAB_ / 4,              256, 0, stream>>>(src, dst, hraw, degp_o, aggp);
    k_C<<<B_,                      512, 0, stream>>>(aggp, degp_i, bp, score,
                                                     pm, ps, sel, orow, out);
    k_D<<<NT_ / 16 + E_ / 4 / 256, 256, 0, stream>>>(feat, score, orow, pm, ps,
                                                     src, dst, sel, out);
}